// Round 1
// baseline (757.674 us; speedup 1.0000x reference)
//
#include <hip/hip_runtime.h>
#include <hip/hip_bf16.h>
#include <stdint.h>

// Problem constants (from reference): DEPTH=4, B=4096, H=E=1024
#define DEPTH 4
#define Bb 4096
#define Hh 1024
#define Ee 1024
#define Kd 2048   // E + H
#define Ng 4096   // 4*H

typedef __attribute__((ext_vector_type(8))) short short8;   // 8 bf16 = 4 VGPRs
typedef __attribute__((ext_vector_type(4))) float floatx4;  // MFMA C/D frag
typedef __attribute__((ext_vector_type(4))) float f32x4;

__device__ __forceinline__ float fast_sigmoid(float x) {
  return 1.0f / (1.0f + __expf(-x));
}
__device__ __forceinline__ float fast_tanh(float x) {
  // overflow-safe tanh via exp of negative argument
  float t = __expf(-2.0f * fabsf(x));
  return copysignf((1.0f - t) / (1.0f + t), x);
}

// async global->LDS, 16B per lane; LDS dest semantics: wave-uniform base + lane*16
__device__ __forceinline__ void gload_lds16(const void* g, void* l) {
  __builtin_amdgcn_global_load_lds(
      (const __attribute__((address_space(1))) void*)(uintptr_t)g,
      (__attribute__((address_space(3))) void*)(uint32_t)(uintptr_t)l,
      16, 0, 0);
}

// ---------------------------------------------------------------------------
// W[l][k][n] (f32, [DEPTH][Kd][Ng]) -> Wt[l][n][k] (bf16, [DEPTH][Ng][Kd])
// 32x32 LDS tile transpose, block (32,8)
// ---------------------------------------------------------------------------
__global__ __launch_bounds__(256) void transpose_w_kernel(
    const float* __restrict__ W, __hip_bfloat16* __restrict__ Wt) {
  __shared__ float tile[32][33];
  const int l = blockIdx.z;
  const int n0 = blockIdx.x * 32;
  const int k0 = blockIdx.y * 32;
  const float* Wl = W + (size_t)l * Kd * Ng;
  __hip_bfloat16* Wtl = Wt + (size_t)l * Ng * Kd;
  const int tx = threadIdx.x, ty = threadIdx.y;
#pragma unroll
  for (int q = 0; q < 4; q++) {
    tile[ty + q * 8][tx] = Wl[(size_t)(k0 + ty + q * 8) * Ng + n0 + tx];
  }
  __syncthreads();
#pragma unroll
  for (int q = 0; q < 4; q++) {
    Wtl[(size_t)(n0 + ty + q * 8) * Kd + k0 + tx] =
        __float2bfloat16(tile[tx][ty + q * 8]);
  }
}

// ---------------------------------------------------------------------------
// xh[l] = [bf16(layer_input) | bf16(s_h[l])], layout [DEPTH][Bb][Kd] bf16.
// This kernel fills xh[0][:, :E] from x and xh[l][:, E:] from s_h for all l.
// (xh[l][:, :E] for l>0 is written by the previous layer's epilogue.)
// ---------------------------------------------------------------------------
__global__ __launch_bounds__(256) void prefill_xh_kernel(
    const float* __restrict__ x, const float* __restrict__ s_h,
    __hip_bfloat16* __restrict__ xh) {
  const int idx = blockIdx.x * blockDim.x + threadIdx.x;  // float4 index
  const int XN = Bb * Ee / 4;                             // 2^20
  const int TOTAL = XN + DEPTH * Bb * Hh / 4;
  if (idx >= TOTAL) return;
  const float* srcp;
  __hip_bfloat16* dst;
  if (idx < XN) {
    const int b = idx >> 8;    // Ee/4 = 256
    const int j4 = idx & 255;
    srcp = x + (size_t)idx * 4;
    dst = xh + (size_t)b * Kd + j4 * 4;
  } else {
    const int e4 = idx - XN;
    const int l = e4 >> 20;    // Bb*Hh/4 = 2^20
    const int r = e4 & 0xFFFFF;
    const int b = r >> 8;      // Hh/4 = 256
    const int j4 = r & 255;
    srcp = s_h + (size_t)e4 * 4;
    dst = xh + (size_t)l * Bb * Kd + (size_t)b * Kd + Ee + j4 * 4;
  }
  f32x4 v = *(const f32x4*)srcp;
  union {
    __hip_bfloat16 h[4];
    unsigned long long u;
  } p;
  p.h[0] = __float2bfloat16(v.x);
  p.h[1] = __float2bfloat16(v.y);
  p.h[2] = __float2bfloat16(v.z);
  p.h[3] = __float2bfloat16(v.w);
  *(unsigned long long*)dst = p.u;
}

// ---------------------------------------------------------------------------
// Fused GEMM + LSTM cell for one layer.
// A = xh[l] [Bb][Kd] bf16;  Wt [Ng][Kd] bf16 (row n = gate g*1024 + j)
// Block tile: 128 rows x (4 gates x 32 j). 4 waves in 2x2:
//   wave_m in {0,1}: rows wm*64..; wave_n in {0,1}: j range wn*16..
//   wave N-frag index == gate, so all 4 gates of (row, j) sit in one lane.
// m97 structure: 2 barriers/k-iter, global_load_lds width 16, ds_read_b128.
// ---------------------------------------------------------------------------
__global__ __launch_bounds__(256, 2) void lstm_layer_kernel(
    const __hip_bfloat16* __restrict__ A, const __hip_bfloat16* __restrict__ Wt,
    const float* __restrict__ bias, const float* __restrict__ c_in,
    float* __restrict__ out_h, float* __restrict__ out_c,
    float* __restrict__ out_final, __hip_bfloat16* __restrict__ xh_next) {
  __shared__ __attribute__((aligned(16))) __hip_bfloat16 As[128][32];  // 8KB
  __shared__ __attribute__((aligned(16))) __hip_bfloat16 Bs[128][32];  // 8KB

  const int tid = threadIdx.x;
  const int lane = tid & 63;
  const int wave = tid >> 6;
  const int wm = wave >> 1;
  const int wn = wave & 1;
  const int m0 = blockIdx.y * 128;
  const int j0 = blockIdx.x * 32;

  // staging: 512 chunks of 16B per tile; thread handles chunks tid and tid+256
  const int seg = (tid & 3) * 8;  // element offset of this 16B segment
  const int ra0 = tid >> 2;
  const int ra1 = (tid + 256) >> 2;
  const __hip_bfloat16* a_src0 = A + (size_t)(m0 + ra0) * Kd + seg;
  const __hip_bfloat16* a_src1 = A + (size_t)(m0 + ra1) * Kd + seg;
  // B tile row t -> Wt row n = (t>>5)*1024 + j0 + (t&31)
  const int nb0 = (ra0 >> 5) * Hh + j0 + (ra0 & 31);
  const int nb1 = (ra1 >> 5) * Hh + j0 + (ra1 & 31);
  const __hip_bfloat16* b_src0 = Wt + (size_t)nb0 * Kd + seg;
  const __hip_bfloat16* b_src1 = Wt + (size_t)nb1 * Kd + seg;
  __hip_bfloat16* a_dst0 = &As[0][0] + tid * 8;
  __hip_bfloat16* a_dst1 = &As[0][0] + (tid + 256) * 8;
  __hip_bfloat16* b_dst0 = &Bs[0][0] + tid * 8;
  __hip_bfloat16* b_dst1 = &Bs[0][0] + (tid + 256) * 8;

  floatx4 acc[4][4];  // [m-frag][gate]
#pragma unroll
  for (int mi = 0; mi < 4; mi++)
#pragma unroll
    for (int g = 0; g < 4; g++) acc[mi][g] = floatx4{0.f, 0.f, 0.f, 0.f};

  const int lm = lane & 15;
  const int qk = lane >> 4;

  for (int kt = 0; kt < Kd / 32; kt++) {
    const int koff = kt * 32;
    __syncthreads();  // previous iter's ds_reads done before overwrite
    gload_lds16(a_src0 + koff, a_dst0);
    gload_lds16(a_src1 + koff, a_dst1);
    gload_lds16(b_src0 + koff, b_dst0);
    gload_lds16(b_src1 + koff, b_dst1);
    __syncthreads();  // staging visible (compiler drains vmcnt before barrier)

    short8 afrag[4], bfrag[4];
#pragma unroll
    for (int mi = 0; mi < 4; mi++)
      afrag[mi] = *(const short8*)&As[wm * 64 + mi * 16 + lm][qk * 8];
#pragma unroll
    for (int g = 0; g < 4; g++)
      bfrag[g] = *(const short8*)&Bs[g * 32 + wn * 16 + lm][qk * 8];
#pragma unroll
    for (int mi = 0; mi < 4; mi++)
#pragma unroll
      for (int g = 0; g < 4; g++)
        acc[mi][g] = __builtin_amdgcn_mfma_f32_16x16x32_bf16(
            afrag[mi], bfrag[g], acc[mi][g], 0, 0, 0);
  }

  // Epilogue: per-lane LSTM cell. C/D frag: col = lane&15, row = (lane>>4)*4+r
  const int j = j0 + wn * 16 + lm;  // gate column 0..1023
  const float bi = bias[j];
  const float bf = bias[Hh + j];
  const float bo = bias[2 * Hh + j];
  const float bg = bias[3 * Hh + j];
#pragma unroll
  for (int mi = 0; mi < 4; mi++) {
    const int row0 = m0 + wm * 64 + mi * 16 + qk * 4;
#pragma unroll
    for (int r = 0; r < 4; r++) {
      const int row = row0 + r;
      const float zi = acc[mi][0][r] + bi;
      const float zf = acc[mi][1][r] + bf;
      const float zo = acc[mi][2][r] + bo;
      const float zg = acc[mi][3][r] + bg;
      const float ig = fast_sigmoid(zi);
      const float fg = fast_sigmoid(zf);
      const float og = fast_sigmoid(zo);
      const float gg = fast_tanh(zg);
      const float c = c_in[(size_t)row * Hh + j];
      const float cn = fmaf(c, fg, gg * ig);
      const float hn = fast_tanh(cn) * og;
      out_h[(size_t)row * Hh + j] = hn;
      out_c[(size_t)row * Hh + j] = cn;
      if (xh_next) xh_next[(size_t)row * Kd + j] = __float2bfloat16(hn);
      if (out_final) out_final[(size_t)row * Hh + j] = hn;
    }
  }
}

// ---------------------------------------------------------------------------
extern "C" void kernel_launch(void* const* d_in, const int* in_sizes, int n_in,
                              void* d_out, int out_size, void* d_ws,
                              size_t ws_size, hipStream_t stream) {
  const float* x = (const float*)d_in[0];     // [Bb][Ee]
  const float* s_h = (const float*)d_in[1];   // [DEPTH][Bb][Hh]
  const float* s_c = (const float*)d_in[2];   // [DEPTH][Bb][Hh]
  const float* W = (const float*)d_in[3];     // [DEPTH][Kd][Ng]
  const float* bias = (const float*)d_in[4];  // [DEPTH][Ng]
  float* out = (float*)d_out;

  // Workspace layout: Wt (64 MiB) | xh (64 MiB)  -> needs 128 MiB
  __hip_bfloat16* Wt = (__hip_bfloat16*)d_ws;
  __hip_bfloat16* xh =
      (__hip_bfloat16*)((char*)d_ws + (size_t)DEPTH * Ng * Kd * 2);

  transpose_w_kernel<<<dim3(Ng / 32, Kd / 32, DEPTH), dim3(32, 8), 0, stream>>>(
      W, Wt);
  prefill_xh_kernel<<<(Bb * Ee / 4 + DEPTH * Bb * Hh / 4) / 256, 256, 0,
                      stream>>>(x, s_h, xh);

  float* out_h = out + (size_t)Bb * Ee;               // h stack section
  float* out_c = out_h + (size_t)DEPTH * Bb * Hh;     // c stack section
  for (int l = 0; l < DEPTH; l++) {
    lstm_layer_kernel<<<dim3(Hh / 32, Bb / 128), 256, 0, stream>>>(
        xh + (size_t)l * Bb * Kd, Wt + (size_t)l * Ng * Kd,
        bias + (size_t)l * Ng, s_c + (size_t)l * Bb * Hh,
        out_h + (size_t)l * Bb * Hh, out_c + (size_t)l * Bb * Hh,
        (l == DEPTH - 1) ? out : nullptr,
        (l < DEPTH - 1) ? xh + (size_t)(l + 1) * Bb * Kd : nullptr);
  }
}

// Round 2
// 753.854 us; speedup vs baseline: 1.0051x; 1.0051x over previous
//
#include <hip/hip_runtime.h>
#include <hip/hip_bf16.h>
#include <stdint.h>

// Problem constants (from reference): DEPTH=4, B=4096, H=E=1024
#define DEPTH 4
#define Bb 4096
#define Hh 1024
#define Ee 1024
#define Kd 2048   // E + H
#define Ng 4096   // 4*H

typedef __attribute__((ext_vector_type(8))) short short8;   // 8 bf16 = 4 VGPRs
typedef __attribute__((ext_vector_type(4))) float floatx4;  // MFMA C/D frag
typedef __attribute__((ext_vector_type(4))) float f32x4;

__device__ __forceinline__ float fast_sigmoid(float x) {
  return 1.0f / (1.0f + __expf(-x));
}
__device__ __forceinline__ float fast_tanh(float x) {
  float t = __expf(-2.0f * fabsf(x));
  return copysignf((1.0f - t) / (1.0f + t), x);
}

// async global->LDS, 16B per lane; LDS dest = wave-uniform base + lane*16
__device__ __forceinline__ void gload_lds16(const void* g, void* l) {
  __builtin_amdgcn_global_load_lds(
      (const __attribute__((address_space(1))) void*)(uintptr_t)g,
      (__attribute__((address_space(3))) void*)(uint32_t)(uintptr_t)l,
      16, 0, 0);
}

// ---------------------------------------------------------------------------
// W[l][k][n] (f32) -> Wt[l][n][k] (bf16). Tile 32(k) x 64(n), block 256.
// Reads: float4 coalesced (256B/row). Writes: bf16x8 (16B) along k, 4 lanes
// per n-row -> 64B contiguous segments. LDS tile [32][68]: 16B-aligned rows,
// <=2-way store conflicts, 4-way read conflicts on cheap ds_read_b32s.
// ---------------------------------------------------------------------------
__global__ __launch_bounds__(256) void transpose_w_kernel(
    const float* __restrict__ W, __hip_bfloat16* __restrict__ Wt) {
  __shared__ __attribute__((aligned(16))) float tile[32][68];
  const int l = blockIdx.z;
  const int k0 = blockIdx.x * 32;
  const int n0 = blockIdx.y * 64;
  const float* Wl = W + (size_t)l * Kd * Ng + (size_t)k0 * Ng + n0;
  __hip_bfloat16* Wtl = Wt + (size_t)l * Ng * Kd;
  const int tid = threadIdx.x;
  {
    const int c0 = tid, c1 = tid + 256;
    const f32x4 v0 = *(const f32x4*)(Wl + (size_t)(c0 >> 4) * Ng + (c0 & 15) * 4);
    const f32x4 v1 = *(const f32x4*)(Wl + (size_t)(c1 >> 4) * Ng + (c1 & 15) * 4);
    *(f32x4*)&tile[c0 >> 4][(c0 & 15) * 4] = v0;
    *(f32x4*)&tile[c1 >> 4][(c1 & 15) * 4] = v1;
  }
  __syncthreads();
  const int n = tid >> 2;   // 0..63
  const int kc = tid & 3;   // 0..3
  union {
    __hip_bfloat16 h[8];
    short8 s;
  } p;
#pragma unroll
  for (int i = 0; i < 8; i++) p.h[i] = __float2bfloat16(tile[kc * 8 + i][n]);
  *(short8*)&Wtl[(size_t)(n0 + n) * Kd + k0 + kc * 8] = p.s;
}

// ---------------------------------------------------------------------------
// xh[l] = [bf16(layer_input) | bf16(s_h[l])], layout [DEPTH][Bb][Kd] bf16.
// Fills xh[0][:, :E] from x and xh[l][:, E:] from s_h for all l.
// ---------------------------------------------------------------------------
__global__ __launch_bounds__(256) void prefill_xh_kernel(
    const float* __restrict__ x, const float* __restrict__ s_h,
    __hip_bfloat16* __restrict__ xh) {
  const int idx = blockIdx.x * blockDim.x + threadIdx.x;  // float4 index
  const int XN = Bb * Ee / 4;                             // 2^20
  const int TOTAL = XN + DEPTH * Bb * Hh / 4;
  if (idx >= TOTAL) return;
  const float* srcp;
  __hip_bfloat16* dst;
  if (idx < XN) {
    const int b = idx >> 8;  // Ee/4 = 256
    const int j4 = idx & 255;
    srcp = x + (size_t)idx * 4;
    dst = xh + (size_t)b * Kd + j4 * 4;
  } else {
    const int e4 = idx - XN;
    const int l = e4 >> 20;  // Bb*Hh/4 = 2^20
    const int r = e4 & 0xFFFFF;
    const int b = r >> 8;  // Hh/4 = 256
    const int j4 = r & 255;
    srcp = s_h + (size_t)e4 * 4;
    dst = xh + (size_t)l * Bb * Kd + (size_t)b * Kd + Ee + j4 * 4;
  }
  f32x4 v = *(const f32x4*)srcp;
  union {
    __hip_bfloat16 h[4];
    unsigned long long u;
  } p;
  p.h[0] = __float2bfloat16(v.x);
  p.h[1] = __float2bfloat16(v.y);
  p.h[2] = __float2bfloat16(v.z);
  p.h[3] = __float2bfloat16(v.w);
  *(unsigned long long*)dst = p.u;
}

// ---------------------------------------------------------------------------
// Fused GEMM + LSTM cell for one layer.
// A = xh[l] [Bb][Kd] bf16;  Wt [Ng][Kd] bf16 (row n = gate g*1024 + j)
// Block tile: 128 rows x (4 gates x 32 j). Wave N-frag index == gate, so all
// 4 gates of (row, j) sit in one lane -> pure per-lane epilogue.
//
// LDS swizzle: tile is 512 linear 16B slots; phys slot s holds logical
// (row = s>>2, chunk = (s&3) ^ ((s>>1 >> 1)&3))  [chunk = 8 k-elements].
// Applied on the GLOBAL source side of global_load_lds (LDS dests must stay
// lane-linear). Fragment ds_read_b128: 16 rows/quad-group -> 8 bank-groups
// x 2-way aliasing = conflict-free (2-way is free per m136).
// ---------------------------------------------------------------------------
__global__ __launch_bounds__(256, 2) void lstm_layer_kernel(
    const __hip_bfloat16* __restrict__ A, const __hip_bfloat16* __restrict__ Wt,
    const float* __restrict__ bias, const float* __restrict__ c_in,
    float* __restrict__ out_h, float* __restrict__ out_c,
    float* __restrict__ out_final, __hip_bfloat16* __restrict__ xh_next) {
  __shared__ __attribute__((aligned(16))) __hip_bfloat16 As[128 * 32];  // 8KB
  __shared__ __attribute__((aligned(16))) __hip_bfloat16 Bs[128 * 32];  // 8KB

  const int tid = threadIdx.x;
  const int lane = tid & 63;
  const int wave = tid >> 6;
  const int wm = wave >> 1;
  const int wn = wave & 1;
  const int m0 = blockIdx.y * 128;
  const int j0 = blockIdx.x * 32;

  // staging: 512 phys slots of 16B per tile; thread handles slots tid, tid+256
  const int s0 = tid, s1 = tid + 256;
  const int r0 = s0 >> 2, q0 = (s0 & 3) ^ ((r0 >> 1) & 3);
  const int r1 = s1 >> 2, q1 = (s1 & 3) ^ ((r1 >> 1) & 3);
  const __hip_bfloat16* a_src0 = A + (size_t)(m0 + r0) * Kd + q0 * 8;
  const __hip_bfloat16* a_src1 = A + (size_t)(m0 + r1) * Kd + q1 * 8;
  // B tile row t -> Wt row n = (t>>5)*1024 + j0 + (t&31)
  const int nb0 = (r0 >> 5) * Hh + j0 + (r0 & 31);
  const int nb1 = (r1 >> 5) * Hh + j0 + (r1 & 31);
  const __hip_bfloat16* b_src0 = Wt + (size_t)nb0 * Kd + q0 * 8;
  const __hip_bfloat16* b_src1 = Wt + (size_t)nb1 * Kd + q1 * 8;
  __hip_bfloat16* a_dst0 = As + s0 * 8;
  __hip_bfloat16* a_dst1 = As + s1 * 8;
  __hip_bfloat16* b_dst0 = Bs + s0 * 8;
  __hip_bfloat16* b_dst1 = Bs + s1 * 8;

  floatx4 acc[4][4];  // [m-frag][gate]
#pragma unroll
  for (int mi = 0; mi < 4; mi++)
#pragma unroll
    for (int g = 0; g < 4; g++) acc[mi][g] = floatx4{0.f, 0.f, 0.f, 0.f};

  const int lm = lane & 15;
  const int qk = lane >> 4;

  // Precompute swizzled frag slot offsets (element offsets into As/Bs)
  int a_off[4], b_off[4];
#pragma unroll
  for (int mi = 0; mi < 4; mi++) {
    const int R = wm * 64 + mi * 16 + lm;
    a_off[mi] = (R * 4 + (qk ^ ((R >> 1) & 3))) * 8;
  }
#pragma unroll
  for (int g = 0; g < 4; g++) {
    const int T = g * 32 + wn * 16 + lm;
    b_off[g] = (T * 4 + (qk ^ ((T >> 1) & 3))) * 8;
  }

  for (int kt = 0; kt < Kd / 32; kt++) {
    const int koff = kt * 32;
    __syncthreads();  // previous iter's ds_reads done before overwrite
    gload_lds16(a_src0 + koff, a_dst0);
    gload_lds16(a_src1 + koff, a_dst1);
    gload_lds16(b_src0 + koff, b_dst0);
    gload_lds16(b_src1 + koff, b_dst1);
    __syncthreads();  // staging visible (compiler drains vmcnt before barrier)

    short8 afrag[4], bfrag[4];
#pragma unroll
    for (int mi = 0; mi < 4; mi++) afrag[mi] = *(const short8*)&As[a_off[mi]];
#pragma unroll
    for (int g = 0; g < 4; g++) bfrag[g] = *(const short8*)&Bs[b_off[g]];
#pragma unroll
    for (int mi = 0; mi < 4; mi++)
#pragma unroll
      for (int g = 0; g < 4; g++)
        acc[mi][g] = __builtin_amdgcn_mfma_f32_16x16x32_bf16(
            afrag[mi], bfrag[g], acc[mi][g], 0, 0, 0);
  }

  // Epilogue: per-lane LSTM cell. C/D frag: col = lane&15, row = (lane>>4)*4+r
  const int j = j0 + wn * 16 + lm;  // gate column 0..1023
  const float bi = bias[j];
  const float bf = bias[Hh + j];
  const float bo = bias[2 * Hh + j];
  const float bg = bias[3 * Hh + j];
#pragma unroll
  for (int mi = 0; mi < 4; mi++) {
    const int row0 = m0 + wm * 64 + mi * 16 + qk * 4;
#pragma unroll
    for (int r = 0; r < 4; r++) {
      const int row = row0 + r;
      const float zi = acc[mi][0][r] + bi;
      const float zf = acc[mi][1][r] + bf;
      const float zo = acc[mi][2][r] + bo;
      const float zg = acc[mi][3][r] + bg;
      const float ig = fast_sigmoid(zi);
      const float fg = fast_sigmoid(zf);
      const float og = fast_sigmoid(zo);
      const float gg = fast_tanh(zg);
      const float c = c_in[(size_t)row * Hh + j];
      const float cn = fmaf(c, fg, gg * ig);
      const float hn = fast_tanh(cn) * og;
      out_h[(size_t)row * Hh + j] = hn;
      out_c[(size_t)row * Hh + j] = cn;
      if (xh_next) xh_next[(size_t)row * Kd + j] = __float2bfloat16(hn);
      if (out_final) out_final[(size_t)row * Hh + j] = hn;
    }
  }
}

// ---------------------------------------------------------------------------
extern "C" void kernel_launch(void* const* d_in, const int* in_sizes, int n_in,
                              void* d_out, int out_size, void* d_ws,
                              size_t ws_size, hipStream_t stream) {
  const float* x = (const float*)d_in[0];     // [Bb][Ee]
  const float* s_h = (const float*)d_in[1];   // [DEPTH][Bb][Hh]
  const float* s_c = (const float*)d_in[2];   // [DEPTH][Bb][Hh]
  const float* W = (const float*)d_in[3];     // [DEPTH][Kd][Ng]
  const float* bias = (const float*)d_in[4];  // [DEPTH][Ng]
  float* out = (float*)d_out;

  // Workspace layout: Wt (64 MiB) | xh (64 MiB)  -> needs 128 MiB
  __hip_bfloat16* Wt = (__hip_bfloat16*)d_ws;
  __hip_bfloat16* xh =
      (__hip_bfloat16*)((char*)d_ws + (size_t)DEPTH * Ng * Kd * 2);

  transpose_w_kernel<<<dim3(Kd / 32, Ng / 64, DEPTH), 256, 0, stream>>>(W, Wt);
  prefill_xh_kernel<<<(Bb * Ee / 4 + DEPTH * Bb * Hh / 4) / 256, 256, 0,
                      stream>>>(x, s_h, xh);

  float* out_h = out + (size_t)Bb * Ee;            // h stack section
  float* out_c = out_h + (size_t)DEPTH * Bb * Hh;  // c stack section
  for (int l = 0; l < DEPTH; l++) {
    lstm_layer_kernel<<<dim3(Hh / 32, Bb / 128), 256, 0, stream>>>(
        xh + (size_t)l * Bb * Kd, Wt + (size_t)l * Ng * Kd,
        bias + (size_t)l * Ng, s_c + (size_t)l * Bb * Hh,
        out_h + (size_t)l * Bb * Hh, out_c + (size_t)l * Bb * Hh,
        (l == DEPTH - 1) ? out : nullptr,
        (l < DEPTH - 1) ? xh + (size_t)(l + 1) * Bb * Kd : nullptr);
  }
}

// Round 3
// 752.338 us; speedup vs baseline: 1.0071x; 1.0020x over previous
//
#include <hip/hip_runtime.h>
#include <hip/hip_bf16.h>
#include <stdint.h>

// Problem constants (from reference): DEPTH=4, B=4096, H=E=1024
#define DEPTH 4
#define Bb 4096
#define Hh 1024
#define Ee 1024
#define Kd 2048   // E + H
#define Ng 4096   // 4*H

typedef __attribute__((ext_vector_type(8))) short short8;   // 8 bf16 = 4 VGPRs
typedef __attribute__((ext_vector_type(4))) float floatx4;  // MFMA C/D frag
typedef __attribute__((ext_vector_type(4))) float f32x4;

__device__ __forceinline__ float fast_sigmoid(float x) {
  return 1.0f / (1.0f + __expf(-x));
}
__device__ __forceinline__ float fast_tanh(float x) {
  float t = __expf(-2.0f * fabsf(x));
  return copysignf((1.0f - t) / (1.0f + t), x);
}

// async global->LDS, 16B per lane; LDS dest = wave-uniform base + lane*16
__device__ __forceinline__ void gload_lds16(const void* g, void* l) {
  __builtin_amdgcn_global_load_lds(
      (const __attribute__((address_space(1))) void*)(uintptr_t)g,
      (__attribute__((address_space(3))) void*)(uint32_t)(uintptr_t)l,
      16, 0, 0);
}

// ---------------------------------------------------------------------------
// W[l][k][n] (f32) -> Wt[l][n][k] (bf16). Tile 128(k) x 64(n), block 256.
// Phase 1: coalesced float4 row reads (256B/row), scatter into n-major LDS
//          (stride 132 f32, 32B-group XOR swizzle -> ~4-way write conflicts).
// Phase 2: each 16-lane group emits one n-row's 256B of Wt CONTIGUOUSLY
//          (16 x 16B bf16x8 stores); LDS reads are within-row, conflict-light.
// ---------------------------------------------------------------------------
__global__ __launch_bounds__(256) void transpose_w_kernel(
    const float* __restrict__ W, __hip_bfloat16* __restrict__ Wt) {
  __shared__ __attribute__((aligned(16))) float ldsT[64 * 132];  // 33 KB
  const int l = blockIdx.z;
  const int k0 = blockIdx.x * 128;
  const int n0 = blockIdx.y * 64;
  const float* Wl = W + (size_t)l * Kd * Ng + (size_t)k0 * Ng + n0;
  __hip_bfloat16* Wtl = Wt + (size_t)l * Ng * Kd;
  const int tid = threadIdx.x;

#pragma unroll
  for (int i = 0; i < 8; i++) {
    const int flat = tid + 256 * i;
    const int k = flat >> 4;            // 0..127
    const int c4 = (flat & 15) * 4;     // n offset 0..60
    const f32x4 v = *(const f32x4*)(Wl + (size_t)k * Ng + c4);
    const int grp = k >> 3;             // 8-f32 (32B) group along k
    const int klo = k & 7;
#pragma unroll
    for (int j = 0; j < 4; j++) {
      const int n = c4 + j;
      ldsT[n * 132 + ((grp ^ ((n >> 2) & 3)) << 3) + klo] = v[j];
    }
  }
  __syncthreads();

#pragma unroll
  for (int i = 0; i < 4; i++) {
    const int c = tid + 256 * i;
    const int n = c >> 4;     // 0..63
    const int kc = c & 15;    // 16B output chunk = 8 k
    const int g = kc ^ ((n >> 2) & 3);
    const float* src = &ldsT[n * 132 + (g << 3)];
    const f32x4 u0 = *(const f32x4*)src;
    const f32x4 u1 = *(const f32x4*)(src + 4);
    union {
      __hip_bfloat16 h[8];
      short8 s;
    } p;
    p.h[0] = __float2bfloat16(u0.x);
    p.h[1] = __float2bfloat16(u0.y);
    p.h[2] = __float2bfloat16(u0.z);
    p.h[3] = __float2bfloat16(u0.w);
    p.h[4] = __float2bfloat16(u1.x);
    p.h[5] = __float2bfloat16(u1.y);
    p.h[6] = __float2bfloat16(u1.z);
    p.h[7] = __float2bfloat16(u1.w);
    *(short8*)&Wtl[(size_t)(n0 + n) * Kd + k0 + kc * 8] = p.s;
  }
}

// ---------------------------------------------------------------------------
// xh[l] = [bf16(layer_input) | bf16(s_h[l])], layout [DEPTH][Bb][Kd] bf16.
// Fills xh[0][:, :E] from x and xh[l][:, E:] from s_h for all l.
// ---------------------------------------------------------------------------
__global__ __launch_bounds__(256) void prefill_xh_kernel(
    const float* __restrict__ x, const float* __restrict__ s_h,
    __hip_bfloat16* __restrict__ xh) {
  const int idx = blockIdx.x * blockDim.x + threadIdx.x;  // float4 index
  const int XN = Bb * Ee / 4;                             // 2^20
  const int TOTAL = XN + DEPTH * Bb * Hh / 4;
  if (idx >= TOTAL) return;
  const float* srcp;
  __hip_bfloat16* dst;
  if (idx < XN) {
    const int b = idx >> 8;  // Ee/4 = 256
    const int j4 = idx & 255;
    srcp = x + (size_t)idx * 4;
    dst = xh + (size_t)b * Kd + j4 * 4;
  } else {
    const int e4 = idx - XN;
    const int l = e4 >> 20;  // Bb*Hh/4 = 2^20
    const int r = e4 & 0xFFFFF;
    const int b = r >> 8;  // Hh/4 = 256
    const int j4 = r & 255;
    srcp = s_h + (size_t)e4 * 4;
    dst = xh + (size_t)l * Bb * Kd + (size_t)b * Kd + Ee + j4 * 4;
  }
  f32x4 v = *(const f32x4*)srcp;
  union {
    __hip_bfloat16 h[4];
    unsigned long long u;
  } p;
  p.h[0] = __float2bfloat16(v.x);
  p.h[1] = __float2bfloat16(v.y);
  p.h[2] = __float2bfloat16(v.z);
  p.h[3] = __float2bfloat16(v.w);
  *(unsigned long long*)dst = p.u;
}

// ---------------------------------------------------------------------------
// Fused GEMM + LSTM cell for one layer.
// A = xh[l] [Bb][Kd] bf16;  Wt [Ng][Kd] bf16 (row n = gate g*1024 + j)
// Block tile: 128 rows x (4 gates x 32 j). Wave N-frag index == gate, so all
// 4 gates of (row, j) sit in one lane -> pure per-lane epilogue.
// LDS XOR swizzle (verified R1: bank conflicts = 0), global_load_lds w=16.
// (256,4): regs 60V+64A=124 <= 128 -> 4 blocks/CU residency for stall cover.
// ---------------------------------------------------------------------------
__global__ __launch_bounds__(256, 4) void lstm_layer_kernel(
    const __hip_bfloat16* __restrict__ A, const __hip_bfloat16* __restrict__ Wt,
    const float* __restrict__ bias, const float* __restrict__ c_in,
    float* __restrict__ out_h, float* __restrict__ out_c,
    float* __restrict__ out_final, __hip_bfloat16* __restrict__ xh_next) {
  __shared__ __attribute__((aligned(16))) __hip_bfloat16 As[128 * 32];  // 8KB
  __shared__ __attribute__((aligned(16))) __hip_bfloat16 Bs[128 * 32];  // 8KB

  const int tid = threadIdx.x;
  const int lane = tid & 63;
  const int wave = tid >> 6;
  const int wm = wave >> 1;
  const int wn = wave & 1;
  const int m0 = blockIdx.y * 128;
  const int j0 = blockIdx.x * 32;

  // staging: 512 phys slots of 16B per tile; thread handles slots tid, tid+256
  const int s0 = tid, s1 = tid + 256;
  const int r0 = s0 >> 2, q0 = (s0 & 3) ^ ((r0 >> 1) & 3);
  const int r1 = s1 >> 2, q1 = (s1 & 3) ^ ((r1 >> 1) & 3);
  const __hip_bfloat16* a_src0 = A + (size_t)(m0 + r0) * Kd + q0 * 8;
  const __hip_bfloat16* a_src1 = A + (size_t)(m0 + r1) * Kd + q1 * 8;
  const int nb0 = (r0 >> 5) * Hh + j0 + (r0 & 31);
  const int nb1 = (r1 >> 5) * Hh + j0 + (r1 & 31);
  const __hip_bfloat16* b_src0 = Wt + (size_t)nb0 * Kd + q0 * 8;
  const __hip_bfloat16* b_src1 = Wt + (size_t)nb1 * Kd + q1 * 8;
  __hip_bfloat16* a_dst0 = As + s0 * 8;
  __hip_bfloat16* a_dst1 = As + s1 * 8;
  __hip_bfloat16* b_dst0 = Bs + s0 * 8;
  __hip_bfloat16* b_dst1 = Bs + s1 * 8;

  floatx4 acc[4][4];  // [m-frag][gate]
#pragma unroll
  for (int mi = 0; mi < 4; mi++)
#pragma unroll
    for (int g = 0; g < 4; g++) acc[mi][g] = floatx4{0.f, 0.f, 0.f, 0.f};

  const int lm = lane & 15;
  const int qk = lane >> 4;

  // Precompute swizzled frag slot offsets (element offsets into As/Bs)
  int a_off[4], b_off[4];
#pragma unroll
  for (int mi = 0; mi < 4; mi++) {
    const int R = wm * 64 + mi * 16 + lm;
    a_off[mi] = (R * 4 + (qk ^ ((R >> 1) & 3))) * 8;
  }
#pragma unroll
  for (int g = 0; g < 4; g++) {
    const int T = g * 32 + wn * 16 + lm;
    b_off[g] = (T * 4 + (qk ^ ((T >> 1) & 3))) * 8;
  }

  for (int kt = 0; kt < Kd / 32; kt++) {
    const int koff = kt * 32;
    __syncthreads();  // previous iter's ds_reads done before overwrite
    gload_lds16(a_src0 + koff, a_dst0);
    gload_lds16(a_src1 + koff, a_dst1);
    gload_lds16(b_src0 + koff, b_dst0);
    gload_lds16(b_src1 + koff, b_dst1);
    __syncthreads();  // staging visible (compiler drains vmcnt before barrier)

    short8 afrag[4], bfrag[4];
#pragma unroll
    for (int mi = 0; mi < 4; mi++) afrag[mi] = *(const short8*)&As[a_off[mi]];
#pragma unroll
    for (int g = 0; g < 4; g++) bfrag[g] = *(const short8*)&Bs[b_off[g]];
#pragma unroll
    for (int mi = 0; mi < 4; mi++)
#pragma unroll
      for (int g = 0; g < 4; g++)
        acc[mi][g] = __builtin_amdgcn_mfma_f32_16x16x32_bf16(
            afrag[mi], bfrag[g], acc[mi][g], 0, 0, 0);
  }

  // Epilogue: per-lane LSTM cell. C/D frag: col = lane&15, row = (lane>>4)*4+r
  const int j = j0 + wn * 16 + lm;  // gate column 0..1023
  const float bi = bias[j];
  const float bf = bias[Hh + j];
  const float bo = bias[2 * Hh + j];
  const float bg = bias[3 * Hh + j];
#pragma unroll
  for (int mi = 0; mi < 4; mi++) {
    const int row0 = m0 + wm * 64 + mi * 16 + qk * 4;
#pragma unroll
    for (int r = 0; r < 4; r++) {
      const int row = row0 + r;
      const float zi = acc[mi][0][r] + bi;
      const float zf = acc[mi][1][r] + bf;
      const float zo = acc[mi][2][r] + bo;
      const float zg = acc[mi][3][r] + bg;
      const float ig = fast_sigmoid(zi);
      const float fg = fast_sigmoid(zf);
      const float og = fast_sigmoid(zo);
      const float gg = fast_tanh(zg);
      const float c = c_in[(size_t)row * Hh + j];
      const float cn = fmaf(c, fg, gg * ig);
      const float hn = fast_tanh(cn) * og;
      out_h[(size_t)row * Hh + j] = hn;
      out_c[(size_t)row * Hh + j] = cn;
      if (xh_next) xh_next[(size_t)row * Kd + j] = __float2bfloat16(hn);
      if (out_final) out_final[(size_t)row * Hh + j] = hn;
    }
  }
}

// ---------------------------------------------------------------------------
extern "C" void kernel_launch(void* const* d_in, const int* in_sizes, int n_in,
                              void* d_out, int out_size, void* d_ws,
                              size_t ws_size, hipStream_t stream) {
  const float* x = (const float*)d_in[0];     // [Bb][Ee]
  const float* s_h = (const float*)d_in[1];   // [DEPTH][Bb][Hh]
  const float* s_c = (const float*)d_in[2];   // [DEPTH][Bb][Hh]
  const float* W = (const float*)d_in[3];     // [DEPTH][Kd][Ng]
  const float* bias = (const float*)d_in[4];  // [DEPTH][Ng]
  float* out = (float*)d_out;

  // Workspace layout: Wt (64 MiB) | xh (64 MiB)  -> needs 128 MiB
  __hip_bfloat16* Wt = (__hip_bfloat16*)d_ws;
  __hip_bfloat16* xh =
      (__hip_bfloat16*)((char*)d_ws + (size_t)DEPTH * Ng * Kd * 2);

  transpose_w_kernel<<<dim3(Kd / 128, Ng / 64, DEPTH), 256, 0, stream>>>(W, Wt);
  prefill_xh_kernel<<<(Bb * Ee / 4 + DEPTH * Bb * Hh / 4) / 256, 256, 0,
                      stream>>>(x, s_h, xh);

  float* out_h = out + (size_t)Bb * Ee;            // h stack section
  float* out_c = out_h + (size_t)DEPTH * Bb * Hh;  // c stack section
  for (int l = 0; l < DEPTH; l++) {
    lstm_layer_kernel<<<dim3(Hh / 32, Bb / 128), 256, 0, stream>>>(
        xh + (size_t)l * Bb * Kd, Wt + (size_t)l * Ng * Kd,
        bias + (size_t)l * Ng, s_c + (size_t)l * Bb * Hh,
        out_h + (size_t)l * Bb * Hh, out_c + (size_t)l * Bb * Hh,
        (l == DEPTH - 1) ? out : nullptr,
        (l < DEPTH - 1) ? xh + (size_t)(l + 1) * Bb * Kd : nullptr);
  }
}